// Round 1
// baseline (3667.177 us; speedup 1.0000x reference)
//
#include <hip/hip_runtime.h>
#include <cstdint>
#include <cstddef>

// PlainRNN fused: h_{t+1} = tanh(h_t @ W_eff + b_eff), traj[t] = h_t @ W_h2o + b_h2o
// W_eff = W_h2h + W_h2o @ W_i2h  (recurrence composition removes x from the loop)
//
// Persistent kernel: 16 groups (16 batch rows each) x 16 blocks (72 of 1152 cols each).
// Groups formed DYNAMICALLY per-XCD (HW_REG_XCC_ID + per-XCD slot counter): all 16
// members share one XCD L2.
//
// R6: decentralized per-WAVE flag barrier, entirely in the XCD-local L2.
//   - R5's atomicAdd(cnt)+serial poll paid: device-scope RMW past the XCD L2,
//     16-way RMW serialization on one line, s_sleep-quantized single-thread
//     detection, and 2 extra __syncthreads per step. All removed.
//   - Producer: after pass-1 h stores, per-wave `s_waitcnt vmcnt(0)` (stores are
//     complete in L2), then lane0 agent-relaxed atomic-store of t into its own
//     flag word. Idempotent stores, no RMW.
//   - Consumer: all 64 lanes poll the group's 64 flags with agent-relaxed atomic
//     loads (sc0 -> L1 bypass -> XCD L2; R4 froze because workgroup-scope loads
//     did NOT bypass L1 — R1/R5 proved the agent-load pairing works). One
//     coalesced 64-lane load per poll iteration (2 cache lines).
//   - red[] LDS reduce scratch double-buffered by step parity => only ONE
//     __syncthreads per step (the reduce barrier). Safety: writers of red[p] at
//     step t+2 are gated on flags >= t+1, which implies every step-t reader of
//     red[p] already published flag t and finished reading.
//   h data: unchanged — plain stores into XCD L2; consumers use PLAIN loads +
//   4-slot hbuf rotation (128KB/step streamed through the 32KB L1 => A-lines
//   capacity-evicted => loads miss L1 and hit the shared L2, always fresh).

#define BATCH  256
#define INPUT  128
#define HIDDEN 1024
#define OUTPUT 128
#define TSTEPS 512
#define NCAT   1152
#define NTILE  72
#define GROUPS 16
#define MEMB   16
#define NSLOT  4

// workspace layout (bytes)
#define WS_WFRAG 0u
#define WS_BEFF  2621440u
#define WS_HBUF  2629632u                 // 4 slots x 256x1024 f16 = 4x524288
#define WS_BAR   4726784u
// bar[] u32: [g*64 + mem*4 + wv]  per-wave step flags (16 groups x 64 = 1024)
//            [1024 + xcc*32]      per-XCD slot counters (one-time)
#define BAR_U32S 1280

typedef _Float16 f16;
typedef _Float16 v8h __attribute__((ext_vector_type(8)));
typedef float    v4f __attribute__((ext_vector_type(4)));

__device__ __forceinline__ float fast_tanh(float x){
  float e = __expf(2.0f * x);
  return (e - 1.0f) / (e + 1.0f);
}

// ---- bias composition
__global__ void k_bias(const float* __restrict__ bi2h, const float* __restrict__ bh2h,
                       const float* __restrict__ bh2o, const float* __restrict__ Wi2h,
                       float* __restrict__ beff){
  int n = blockIdx.x*256 + threadIdx.x;
  if (n >= 1168) return;
  float v = 0.f;
  if (n < HIDDEN){
    v = bi2h[n] + bh2h[n];
    for (int j=0;j<INPUT;j++) v += bh2o[j]*Wi2h[j*HIDDEN + n];
  } else if (n < NCAT){
    v = bh2o[n - HIDDEN];
  }
  beff[n] = v;
}

// ---- h_1 = tanh(x0 @ W_i2h + b_i2h + b_h2h) -> slot 0
__global__ void k_h1(const float* __restrict__ x0, const float* __restrict__ Wi2h,
                     const float* __restrict__ bi2h, const float* __restrict__ bh2h,
                     f16* __restrict__ hbuf){
  int idx = blockIdx.x*256 + threadIdx.x;
  int m = idx >> 10, n = idx & 1023;
  float acc = bi2h[n] + bh2h[n];
  const float* xr = x0 + m*INPUT;
  for (int j=0;j<INPUT;j++) acc += xr[j]*Wi2h[j*HIDDEN + n];
  hbuf[idx] = (f16)fast_tanh(acc);
}

// ---- traj[0] = x_0
__global__ void k_copy0(const float* __restrict__ x0, float* __restrict__ out){
  int i = blockIdx.x*256 + threadIdx.x;
  out[i] = x0[i];
}

// ---- W fragment packing: [mem 16][wave 4][kk 8][c 5][lane 64][8 halves]
__global__ void k_wfrag(const float* __restrict__ Wh2h, const float* __restrict__ Wh2o,
                        const float* __restrict__ Wi2h, f16* __restrict__ Wfrag){
  int gid = blockIdx.x*256 + threadIdx.x;
  int lane = gid & 63;
  int fi = gid >> 6;
  int c = fi % 5, kk = (fi/5) & 7, wv = (fi/40) & 3, mem = fi/160;
  int k0 = wv*256 + kk*32 + (lane>>4)*8;
  int n  = mem*NTILE + c*16 + (lane & 15);
  f16 vals[8];
  if (n >= NCAT){
    #pragma unroll
    for (int j=0;j<8;j++) vals[j] = (f16)0.f;
  } else if (n >= HIDDEN){
    #pragma unroll
    for (int j=0;j<8;j++) vals[j] = (f16)Wh2o[(k0+j)*OUTPUT + (n-HIDDEN)];
  } else {
    float acc[8];
    #pragma unroll
    for (int j=0;j<8;j++) acc[j] = Wh2h[(k0+j)*HIDDEN + n];
    for (int q=0;q<INPUT;q++){
      float wi = Wi2h[q*HIDDEN + n];
      #pragma unroll
      for (int j=0;j<8;j++) acc[j] += Wh2o[(k0+j)*OUTPUT + q]*wi;
    }
    #pragma unroll
    for (int j=0;j<8;j++) vals[j] = (f16)acc[j];
  }
  v8h pack;
  #pragma unroll
  for (int j=0;j<8;j++) pack[j] = vals[j];
  *(v8h*)(Wfrag + (size_t)gid*8) = pack;
}

// ---- persistent recurrence kernel: 256 blocks x 256 threads, 1 block/CU (96KB dyn LDS)
__global__ void __launch_bounds__(256, 1)
k_rnn(const f16* __restrict__ Wfrag, const float* __restrict__ beff,
      f16* __restrict__ hbuf, unsigned int* __restrict__ bar,
      float* __restrict__ out){
  extern __shared__ char lds_raw[];
  // red double buffer: parity 0 at +0, parity 1 at +16384 (each 15360 B used)
  unsigned* s_slot = (unsigned*)(lds_raw + 32768);

  const int tid  = threadIdx.x;
  const int lane = tid & 63;
  const int wv   = tid >> 6;

  // Dynamic same-XCD group formation. 1 block/CU + grid==CU count => 32 blocks/XCD.
  // Group = xcc*2 + slot/16, member = slot%16: group shares one XCD L2 BY CONSTRUCTION.
  if (tid == 0){
    unsigned xcc;
    asm volatile("s_getreg_b32 %0, hwreg(HW_REG_XCC_ID)" : "=s"(xcc));
    xcc &= 7;
    unsigned slot = atomicAdd(&bar[1024 + xcc*32], 1u);  // one-time, device-scope
    *s_slot = xcc*32 + (slot & 31u);
  }
  __syncthreads();
  const unsigned sid = *s_slot;
  const int g   = sid >> 4;
  const int mem = sid & 15;
  if (g >= GROUPS) return;
  const int m0   = g * 16;
  const int n0   = mem * NTILE;
  const int quad = lane >> 4;
  const int l15  = lane & 15;

  // B fragments resident in registers for the whole 511-step loop
  v8h bw[8][5];
  {
    const f16* wp = Wfrag + ((size_t)((mem*4 + wv)*40)*64 + lane)*8;
    #pragma unroll
    for (int kk=0;kk<8;kk++)
      #pragma unroll
      for (int c=0;c<5;c++)
        bw[kk][c] = *(const v8h*)(wp + (size_t)((kk*5+c)*64)*8);
  }

  // Per-thread bias for owned columns, hoisted into registers: the per-step
  // beff[col] load always missed L1 (A-stream evicts it) and sat on the
  // critical path right after the reduce. wv0 owns tiles c=0 and c=4.
  float bown[2] = {0.f, 0.f};
  #pragma unroll
  for (int c=0;c<5;c++){
    if ((c & 3) == wv){
      int colT = c*16 + l15;
      int col  = n0 + colT;
      if (colT < NTILE && col < NCAT) bown[c>>2] = beff[col];
    }
  }

  const int kbase = wv*256;
  unsigned int* flg  = bar + g*64;      // 64 per-wave flags, 256 B = 2 lines
  const int   myflag = mem*4 + wv;

  for (int t=1; t<TSTEPS; ++t){
    // ---- wait: all 64 group flags >= t-1. Agent-relaxed atomic loads emit sc0
    // (L1 bypass) and are served by the XCD-local L2 where the flag stores land.
    // One coalesced 64-lane load per iteration => ~150ns detection granularity.
    // Bounded: if broken, ~0.4ms/step => visible absmax failure, never a hang.
    {
      const unsigned target = (unsigned)(t-1);
      unsigned tries = 0;
      for (;;){
        unsigned f = __hip_atomic_load(flg + lane, __ATOMIC_RELAXED,
                                       __HIP_MEMORY_SCOPE_AGENT);
        if (__all((int)(f >= target))) break;
        if (++tries > 4096u) break;
      }
    }

    const f16* hin  = hbuf + (size_t)((t-1)&(NSLOT-1))*(BATCH*HIDDEN);
    f16*       hout = hbuf + (size_t)(t&(NSLOT-1))*(BATCH*HIDDEN);
    float*     red  = (float*)(lds_raw + (size_t)(t & 1)*16384);

    // A fragments: plain vector loads. 4-slot rotation guarantees the L1 line for
    // this address was evicted (128KB/step streamed) => miss L1, hit shared L2.
    v8h af[8];
    {
      const v8h* abase = (const v8h*)(hin + (size_t)(m0 + l15)*HIDDEN + kbase + quad*8);
      #pragma unroll
      for (int kk=0;kk<8;kk++)
        af[kk] = abase[kk*4];            // stride 32 halves = 4 v8h
    }

    v4f acc[5];
    #pragma unroll
    for (int c=0;c<5;c++){ v4f z = {0.f,0.f,0.f,0.f}; acc[c] = z; }

    #pragma unroll
    for (int kk=0;kk<8;kk++){
      #pragma unroll
      for (int c=0;c<5;c++)
        acc[c] = __builtin_amdgcn_mfma_f32_16x16x32_f16(af[kk], bw[kk][c], acc[c], 0,0,0);
    }

    // cross-wave K reduction via LDS (parity-buffered). tile c owner = c&3.
    #pragma unroll
    for (int c=0;c<5;c++){
      int owner = c & 3;
      if (wv != owner){
        int rank = (wv > owner) ? wv-1 : wv;
        *(v4f*)(red + ((size_t)(c*3 + rank)*64 + lane)*4) = acc[c];
      }
    }
    __syncthreads();   // the ONLY block barrier per step: reduce visibility

    // pass 1: hidden columns (consumed by group next step) -> plain stores into L2
    #pragma unroll
    for (int c=0;c<5;c++){
      if ((c & 3) == wv){
        int colT = c*16 + l15;
        int col  = n0 + colT;
        if (col < HIDDEN && colT < NTILE){
          v4f s = acc[c];
          #pragma unroll
          for (int r=0;r<3;r++) s += *(const v4f*)(red + ((size_t)(c*3 + r)*64 + lane)*4);
          float b = bown[c>>2];
          #pragma unroll
          for (int r=0;r<4;r++){
            float v = fast_tanh(s[r] + b);
            hout[(size_t)(m0 + quad*4 + r)*HIDDEN + col] = (f16)v;  // C/D: col=lane&15,row=quad*4+r
          }
        }
      }
    }

    // drain THIS wave's h stores into L2, then publish this wave's flag.
    // Per-wave: no block-wide barrier needed; consumers wait on all 64 flags.
    asm volatile("s_waitcnt vmcnt(0)" ::: "memory");
    if (lane == 0)
      __hip_atomic_store(flg + myflag, (unsigned)t, __ATOMIC_RELAXED,
                         __HIP_MEMORY_SCOPE_AGENT);

    // pass 2: y columns (consumed by nobody) — after the flag, off the critical
    // path; overlaps group-mates' polling. red[t&1] is safe to read: its next
    // writer (step t+2) is gated on flags >= t+1, which this wave hasn't stored.
    #pragma unroll
    for (int c=0;c<5;c++){
      if ((c & 3) == wv){
        int colT = c*16 + l15;
        int col  = n0 + colT;
        if (col >= HIDDEN && colT < NTILE){
          v4f s = acc[c];
          #pragma unroll
          for (int r=0;r<3;r++) s += *(const v4f*)(red + ((size_t)(c*3 + r)*64 + lane)*4);
          float b = bown[c>>2];
          float* op = out + (size_t)t*(BATCH*OUTPUT) + (col - HIDDEN);
          #pragma unroll
          for (int r=0;r<4;r++)
            op[(size_t)(m0 + quad*4 + r)*OUTPUT] = s[r] + b;
        }
      }
    }
  }
}

extern "C" void kernel_launch(void* const* d_in, const int* in_sizes, int n_in,
                              void* d_out, int out_size, void* d_ws, size_t ws_size,
                              hipStream_t stream){
  const float* x0   = (const float*)d_in[0];
  const float* Wi2h = (const float*)d_in[1];
  const float* bi2h = (const float*)d_in[2];
  const float* Wh2h = (const float*)d_in[3];
  const float* bh2h = (const float*)d_in[4];
  const float* Wh2o = (const float*)d_in[5];
  const float* bh2o = (const float*)d_in[6];
  float* out = (float*)d_out;
  char* ws = (char*)d_ws;

  f16*          Wfrag = (f16*)(ws + WS_WFRAG);
  float*        beff  = (float*)(ws + WS_BEFF);
  f16*          hbuf  = (f16*)(ws + WS_HBUF);
  unsigned int* bar   = (unsigned int*)(ws + WS_BAR);

  hipMemsetAsync(bar, 0, BAR_U32S*sizeof(unsigned int), stream);
  k_bias <<<5,    256, 0, stream>>>(bi2h, bh2h, bh2o, Wi2h, beff);
  k_h1   <<<1024, 256, 0, stream>>>(x0, Wi2h, bi2h, bh2h, hbuf);
  k_copy0<<<128,  256, 0, stream>>>(x0, out);
  k_wfrag<<<640,  256, 0, stream>>>(Wh2h, Wh2o, Wi2h, Wfrag);

  // 96KB dynamic LDS forces 1 block/CU -> all 256 blocks co-resident, 32 per XCD,
  // 1 wave/SIMD -> full VGPR budget for register-resident W fragments.
  hipFuncSetAttribute((const void*)k_rnn, hipFuncAttributeMaxDynamicSharedMemorySize, 98304);
  k_rnn<<<256, 256, 98304, stream>>>(Wfrag, beff, hbuf, bar, out);
}

// Round 2
// 1529.896 us; speedup vs baseline: 2.3970x; 2.3970x over previous
//
#include <hip/hip_runtime.h>
#include <cstdint>
#include <cstddef>

// PlainRNN fused: h_{t+1} = tanh(h_t @ W_eff + b_eff), traj[t] = h_t @ W_h2o + b_h2o
// W_eff = W_h2h + W_h2o @ W_i2h  (recurrence composition removes x from the loop)
//
// Persistent kernel: 16 groups (16 batch rows each) x 16 blocks (72 of 1152 cols each).
// Groups formed DYNAMICALLY per-XCD (HW_REG_XCC_ID + per-XCD slot counter): all 16
// members share one XCD L2.
//
// R7 = R5 skeleton + per-member STORE-flag arrival (no RMW) + disciplined poll.
//   R5 (1679us): atomicAdd arrival serialized 16 far-RMWs on one line + s_sleep
//     single-lane poll. Worked, but arrival serialization sat on the step path.
//   R6 (3667us, REGRESSION): per-wave flags were fine, but 1024 waves polled
//     continuously with NO backoff -> device-scope load flood at the coherence
//     point inflated everyone's latency (FETCH +10.7MB, all utils halved).
//   R7: arrival = tid0 agent-relaxed STORE flg[mem]=t after the drain barrier
//     (idempotent, 16 stores on one line, no RMW round-trip). Poll = wave 0
//     ONLY: 64 lanes load flg[lane&15] (one transaction, one line) with
//     s_sleep(1) backoff; waves 1-3 park at the release __syncthreads.
//     16 pollers/line with backoff = R5's proven pressure level.
//   h data unchanged: plain stores -> XCD-local L2 (syncthreads drains vmcnt);
//   consumers use PLAIN loads + 4-slot hbuf rotation (128KB/step streams the
//   32KB L1 => A-lines capacity-evicted => loads miss L1, hit shared L2 fresh).
//   beff hoisted to registers (bown) — the per-step beff load always missed L1
//   and sat right after the reduce on the critical path.

#define BATCH  256
#define INPUT  128
#define HIDDEN 1024
#define OUTPUT 128
#define TSTEPS 512
#define NCAT   1152
#define NTILE  72
#define GROUPS 16
#define MEMB   16
#define NSLOT  4

// workspace layout (bytes)
#define WS_WFRAG 0u
#define WS_BEFF  2621440u
#define WS_HBUF  2629632u                 // 4 slots x 256x1024 f16 = 4x524288
#define WS_BAR   4726784u
// bar[] u32: [g*32 + mem]   per-member step flags (one 128B line per group)
//            [512 + xcc*32] per-XCD slot counters (one-time)
#define BAR_U32S 768

typedef _Float16 f16;
typedef _Float16 v8h __attribute__((ext_vector_type(8)));
typedef float    v4f __attribute__((ext_vector_type(4)));

__device__ __forceinline__ float fast_tanh(float x){
  float e = __expf(2.0f * x);
  return (e - 1.0f) / (e + 1.0f);
}

// ---- bias composition
__global__ void k_bias(const float* __restrict__ bi2h, const float* __restrict__ bh2h,
                       const float* __restrict__ bh2o, const float* __restrict__ Wi2h,
                       float* __restrict__ beff){
  int n = blockIdx.x*256 + threadIdx.x;
  if (n >= 1168) return;
  float v = 0.f;
  if (n < HIDDEN){
    v = bi2h[n] + bh2h[n];
    for (int j=0;j<INPUT;j++) v += bh2o[j]*Wi2h[j*HIDDEN + n];
  } else if (n < NCAT){
    v = bh2o[n - HIDDEN];
  }
  beff[n] = v;
}

// ---- h_1 = tanh(x0 @ W_i2h + b_i2h + b_h2h) -> slot 0
__global__ void k_h1(const float* __restrict__ x0, const float* __restrict__ Wi2h,
                     const float* __restrict__ bi2h, const float* __restrict__ bh2h,
                     f16* __restrict__ hbuf){
  int idx = blockIdx.x*256 + threadIdx.x;
  int m = idx >> 10, n = idx & 1023;
  float acc = bi2h[n] + bh2h[n];
  const float* xr = x0 + m*INPUT;
  for (int j=0;j<INPUT;j++) acc += xr[j]*Wi2h[j*HIDDEN + n];
  hbuf[idx] = (f16)fast_tanh(acc);
}

// ---- traj[0] = x_0
__global__ void k_copy0(const float* __restrict__ x0, float* __restrict__ out){
  int i = blockIdx.x*256 + threadIdx.x;
  out[i] = x0[i];
}

// ---- W fragment packing: [mem 16][wave 4][kk 8][c 5][lane 64][8 halves]
__global__ void k_wfrag(const float* __restrict__ Wh2h, const float* __restrict__ Wh2o,
                        const float* __restrict__ Wi2h, f16* __restrict__ Wfrag){
  int gid = blockIdx.x*256 + threadIdx.x;
  int lane = gid & 63;
  int fi = gid >> 6;
  int c = fi % 5, kk = (fi/5) & 7, wv = (fi/40) & 3, mem = fi/160;
  int k0 = wv*256 + kk*32 + (lane>>4)*8;
  int n  = mem*NTILE + c*16 + (lane & 15);
  f16 vals[8];
  if (n >= NCAT){
    #pragma unroll
    for (int j=0;j<8;j++) vals[j] = (f16)0.f;
  } else if (n >= HIDDEN){
    #pragma unroll
    for (int j=0;j<8;j++) vals[j] = (f16)Wh2o[(k0+j)*OUTPUT + (n-HIDDEN)];
  } else {
    float acc[8];
    #pragma unroll
    for (int j=0;j<8;j++) acc[j] = Wh2h[(k0+j)*HIDDEN + n];
    for (int q=0;q<INPUT;q++){
      float wi = Wi2h[q*HIDDEN + n];
      #pragma unroll
      for (int j=0;j<8;j++) acc[j] += Wh2o[(k0+j)*OUTPUT + q]*wi;
    }
    #pragma unroll
    for (int j=0;j<8;j++) vals[j] = (f16)acc[j];
  }
  v8h pack;
  #pragma unroll
  for (int j=0;j<8;j++) pack[j] = vals[j];
  *(v8h*)(Wfrag + (size_t)gid*8) = pack;
}

// ---- persistent recurrence kernel: 256 blocks x 256 threads, 1 block/CU (96KB dyn LDS)
__global__ void __launch_bounds__(256, 1)
k_rnn(const f16* __restrict__ Wfrag, const float* __restrict__ beff,
      f16* __restrict__ hbuf, unsigned int* __restrict__ bar,
      float* __restrict__ out){
  extern __shared__ char lds_raw[];
  float*    red    = (float*)lds_raw;              // [(c*3+rank)][lane][4] f32, 15360 B
  unsigned* s_slot = (unsigned*)(lds_raw + 16384);

  const int tid  = threadIdx.x;
  const int lane = tid & 63;
  const int wv   = tid >> 6;

  // Dynamic same-XCD group formation. 1 block/CU + grid==CU count => 32 blocks/XCD.
  // Group = xcc*2 + slot/16, member = slot%16: group shares one XCD L2 BY CONSTRUCTION.
  if (tid == 0){
    unsigned xcc;
    asm volatile("s_getreg_b32 %0, hwreg(HW_REG_XCC_ID)" : "=s"(xcc));
    xcc &= 7;
    unsigned slot = atomicAdd(&bar[512 + xcc*32], 1u);  // one-time, device-scope
    *s_slot = xcc*32 + (slot & 31u);
  }
  __syncthreads();
  const unsigned sid = *s_slot;
  const int g   = sid >> 4;
  const int mem = sid & 15;
  if (g >= GROUPS) return;
  const int m0   = g * 16;
  const int n0   = mem * NTILE;
  const int quad = lane >> 4;
  const int l15  = lane & 15;

  // B fragments resident in registers for the whole 511-step loop
  v8h bw[8][5];
  {
    const f16* wp = Wfrag + ((size_t)((mem*4 + wv)*40)*64 + lane)*8;
    #pragma unroll
    for (int kk=0;kk<8;kk++)
      #pragma unroll
      for (int c=0;c<5;c++)
        bw[kk][c] = *(const v8h*)(wp + (size_t)((kk*5+c)*64)*8);
  }

  // Per-thread bias for owned columns hoisted into registers: the per-step
  // beff[col] load always missed L1 (A-stream evicts it) and sat on the
  // critical path right after the reduce. wv0 owns tiles c=0 and c=4.
  float bown[2] = {0.f, 0.f};
  #pragma unroll
  for (int c=0;c<5;c++){
    if ((c & 3) == wv){
      int colT = c*16 + l15;
      int col  = n0 + colT;
      if (colT < NTILE && col < NCAT) bown[c>>2] = beff[col];
    }
  }

  const int kbase = wv*256;
  unsigned int* flg = bar + g*32;   // 16 per-member flags, one 128B line per group

  for (int t=1; t<TSTEPS; ++t){
    // ---- wait: all 16 member flags >= t-1. Wave 0 ONLY polls: 64 lanes load
    // flg[lane&15] (one transaction on one line, agent-relaxed => sc0 => served
    // at the coherence point where the flag stores land), s_sleep(1) backoff.
    // 16 pollers per line with backoff = R5's proven pressure level (R6's
    // 64-pollers-no-backoff flood is what regressed).
    // Bounded: if broken, visible absmax failure, never a hang.
    if (wv == 0){
      const unsigned target = (unsigned)(t-1);
      unsigned tries = 0;
      for (;;){
        unsigned f = __hip_atomic_load(flg + (lane & 15), __ATOMIC_RELAXED,
                                       __HIP_MEMORY_SCOPE_AGENT);
        if (__all((int)(f >= target))) break;
        if (++tries > 2048u) break;
        __builtin_amdgcn_s_sleep(1);
      }
    }
    __syncthreads();   // release: waves 1-3 park here while wave 0 polls

    const f16* hin  = hbuf + (size_t)((t-1)&(NSLOT-1))*(BATCH*HIDDEN);
    f16*       hout = hbuf + (size_t)(t&(NSLOT-1))*(BATCH*HIDDEN);

    // A fragments: plain vector loads. 4-slot rotation guarantees the L1 line for
    // this address was evicted (128KB/step streamed) => miss L1, hit shared L2.
    // lane holds A[m=lane&15][k=quad*8+j]; waves read disjoint K slices.
    v8h af[8];
    {
      const v8h* abase = (const v8h*)(hin + (size_t)(m0 + l15)*HIDDEN + kbase + quad*8);
      #pragma unroll
      for (int kk=0;kk<8;kk++)
        af[kk] = abase[kk*4];            // stride 32 halves = 4 v8h
    }

    v4f acc[5];
    #pragma unroll
    for (int c=0;c<5;c++){ v4f z = {0.f,0.f,0.f,0.f}; acc[c] = z; }

    #pragma unroll
    for (int kk=0;kk<8;kk++){
      #pragma unroll
      for (int c=0;c<5;c++)
        acc[c] = __builtin_amdgcn_mfma_f32_16x16x32_f16(af[kk], bw[kk][c], acc[c], 0,0,0);
    }

    // cross-wave K reduction via LDS. tile c owner = c&3.
    #pragma unroll
    for (int c=0;c<5;c++){
      int owner = c & 3;
      if (wv != owner){
        int rank = (wv > owner) ? wv-1 : wv;
        *(v4f*)(red + ((size_t)(c*3 + rank)*64 + lane)*4) = acc[c];
      }
    }
    __syncthreads();   // reduce visibility

    // pass 1: hidden columns (consumed by group next step) -> plain stores into L2
    #pragma unroll
    for (int c=0;c<5;c++){
      if ((c & 3) == wv){
        int colT = c*16 + l15;
        int col  = n0 + colT;
        if (col < HIDDEN && colT < NTILE){
          v4f s = acc[c];
          #pragma unroll
          for (int r=0;r<3;r++) s += *(const v4f*)(red + ((size_t)(c*3 + r)*64 + lane)*4);
          float b = bown[c>>2];
          #pragma unroll
          for (int r=0;r<4;r++){
            float v = fast_tanh(s[r] + b);
            hout[(size_t)(m0 + quad*4 + r)*HIDDEN + col] = (f16)v;  // C/D: col=lane&15,row=quad*4+r
          }
        }
      }
    }
    __syncthreads();   // drain: each wave waits vmcnt(0) => h stores are in L2

    // arrival: idempotent agent-relaxed STORE (no RMW, no serialization).
    if (tid == 0)
      __hip_atomic_store(flg + mem, (unsigned)t, __ATOMIC_RELAXED,
                         __HIP_MEMORY_SCOPE_AGENT);

    // pass 2: y columns (consumed by nobody) — off the critical path, overlaps
    // group-mates' polling. red stable until next step's post-release writes.
    #pragma unroll
    for (int c=0;c<5;c++){
      if ((c & 3) == wv){
        int colT = c*16 + l15;
        int col  = n0 + colT;
        if (col >= HIDDEN && colT < NTILE){
          v4f s = acc[c];
          #pragma unroll
          for (int r=0;r<3;r++) s += *(const v4f*)(red + ((size_t)(c*3 + r)*64 + lane)*4);
          float b = bown[c>>2];
          float* op = out + (size_t)t*(BATCH*OUTPUT) + (col - HIDDEN);
          #pragma unroll
          for (int r=0;r<4;r++)
            op[(size_t)(m0 + quad*4 + r)*OUTPUT] = s[r] + b;
        }
      }
    }
  }
}

extern "C" void kernel_launch(void* const* d_in, const int* in_sizes, int n_in,
                              void* d_out, int out_size, void* d_ws, size_t ws_size,
                              hipStream_t stream){
  const float* x0   = (const float*)d_in[0];
  const float* Wi2h = (const float*)d_in[1];
  const float* bi2h = (const float*)d_in[2];
  const float* Wh2h = (const float*)d_in[3];
  const float* bh2h = (const float*)d_in[4];
  const float* Wh2o = (const float*)d_in[5];
  const float* bh2o = (const float*)d_in[6];
  float* out = (float*)d_out;
  char* ws = (char*)d_ws;

  f16*          Wfrag = (f16*)(ws + WS_WFRAG);
  float*        beff  = (float*)(ws + WS_BEFF);
  f16*          hbuf  = (f16*)(ws + WS_HBUF);
  unsigned int* bar   = (unsigned int*)(ws + WS_BAR);

  hipMemsetAsync(bar, 0, BAR_U32S*sizeof(unsigned int), stream);
  k_bias <<<5,    256, 0, stream>>>(bi2h, bh2h, bh2o, Wi2h, beff);
  k_h1   <<<1024, 256, 0, stream>>>(x0, Wi2h, bi2h, bh2h, hbuf);
  k_copy0<<<128,  256, 0, stream>>>(x0, out);
  k_wfrag<<<640,  256, 0, stream>>>(Wh2h, Wh2o, Wi2h, Wfrag);

  // 96KB dynamic LDS forces 1 block/CU -> all 256 blocks co-resident, 32 per XCD,
  // 1 wave/SIMD -> full VGPR budget for register-resident W fragments.
  hipFuncSetAttribute((const void*)k_rnn, hipFuncAttributeMaxDynamicSharedMemorySize, 98304);
  k_rnn<<<256, 256, 98304, stream>>>(Wfrag, beff, hbuf, bar, out);
}